// Round 9
// baseline (19206.142 us; speedup 1.0000x reference)
//
#include <hip/hip_runtime.h>

typedef unsigned short ushort_t;
typedef unsigned int uint_t;
typedef unsigned long long u64;
typedef __attribute__((ext_vector_type(8))) short short8;
typedef __attribute__((ext_vector_type(4))) float floatx4;

#define S_LEN 1024
#define BATCH 32
#define HDIM  256
#define GDIM  1024  /* 4H */
#define DIN   128

__device__ __forceinline__ float bf2f(ushort_t u) { return __uint_as_float(((unsigned)u) << 16); }
__device__ __forceinline__ float bf2fs(short s)   { return __uint_as_float(((unsigned)(unsigned short)s) << 16); }
__device__ __forceinline__ ushort_t f2bf(float f) {
  unsigned u = __float_as_uint(f);
  unsigned r = (u + 0x7fffu + ((u >> 16) & 1u)) >> 16;
  return (ushort_t)r;
}
__device__ __forceinline__ float sigf(float x) { return 1.f / (1.f + __expf(-x)); }
__device__ __forceinline__ float tanh_f(float x) {
  float ax = fabsf(x);
  float e = __expf(2.f * ax);
  float r = 1.f - 2.f / (e + 1.f);
  return x < 0.f ? -r : r;
}

__device__ __forceinline__ void load_lds16(const void* g, void* l) {
  __builtin_amdgcn_global_load_lds((const __attribute__((address_space(1))) unsigned int*)g,
                                   (__attribute__((address_space(3))) unsigned int*)l, 16, 0, 0);
}

// ---------------------------------------------------------------------------
// Generic bf16 MFMA GEMM: C[m][n] = sum_k A[m][k]*B[n][k] + bias[n]
// mode 0: bf16 at C[m*N+n]          (h layout [t][b][n], m = t*32+b)
// mode 1: fp32 at out[b][t][n]      (head output)
// mode 2: bf16 at C[t][n][b]        (xp transposed for vectorized recurrence)
// ---------------------------------------------------------------------------
__global__ __launch_bounds__(256) void gemm_bf16(
    const ushort_t* __restrict__ A, const ushort_t* __restrict__ Bw,
    const float* __restrict__ bias, void* __restrict__ Cout,
    int M, int N, int K, int mode)
{
  __shared__ __align__(16) ushort_t As[128 * 64];
  __shared__ __align__(16) ushort_t Bs[128 * 64];
  const int tid = threadIdx.x;
  const int lane = tid & 63, wid = tid >> 6;
  const int wm = wid >> 1, wn = wid & 1;
  const int bm = blockIdx.y, bn = blockIdx.x;
  const int l15 = lane & 15, q4 = lane >> 4;

  const int r  = tid >> 3;
  const int c8 = tid & 7;
  const int g8 = c8 ^ (r & 7);

  floatx4 zero4 = {0.f, 0.f, 0.f, 0.f};
  floatx4 acc[4][4];
#pragma unroll
  for (int mt = 0; mt < 4; ++mt)
#pragma unroll
    for (int nt = 0; nt < 4; ++nt) acc[mt][nt] = zero4;

  for (int k0 = 0; k0 < K; k0 += 64) {
    __syncthreads();
#pragma unroll
    for (int p = 0; p < 4; ++p) {
      int row = p * 32 + r;
      load_lds16(A + (size_t)(bm * 128 + row) * K + k0 + g8 * 8, (void*)(As + p * 2048 + wid * 512));
      load_lds16(Bw + (size_t)(bn * 128 + row) * K + k0 + g8 * 8, (void*)(Bs + p * 2048 + wid * 512));
    }
    __syncthreads();
#pragma unroll
    for (int ks = 0; ks < 2; ++ks) {
      const int kk = ks * 4 + q4;
      short8 af[4], bf[4];
#pragma unroll
      for (int mt = 0; mt < 4; ++mt) {
        int row = wm * 64 + mt * 16 + l15;
        af[mt] = *(const short8*)(As + row * 64 + ((kk ^ (row & 7)) << 3));
      }
#pragma unroll
      for (int nt = 0; nt < 4; ++nt) {
        int row = wn * 64 + nt * 16 + l15;
        bf[nt] = *(const short8*)(Bs + row * 64 + ((kk ^ (row & 7)) << 3));
      }
#pragma unroll
      for (int mt = 0; mt < 4; ++mt)
#pragma unroll
        for (int nt = 0; nt < 4; ++nt)
          acc[mt][nt] = __builtin_amdgcn_mfma_f32_16x16x32_bf16(af[mt], bf[nt], acc[mt][nt], 0, 0, 0);
    }
  }

#pragma unroll
  for (int mt = 0; mt < 4; ++mt)
#pragma unroll
    for (int nt = 0; nt < 4; ++nt)
#pragma unroll
      for (int rr = 0; rr < 4; ++rr) {
        int m = bm * 128 + wm * 64 + mt * 16 + q4 * 4 + rr;
        int n = bn * 128 + wn * 64 + nt * 16 + l15;
        float v = acc[mt][nt][rr] + bias[n];
        if (mode == 0) {
          ((ushort_t*)Cout)[(size_t)m * N + n] = f2bf(v);
        } else if (mode == 1) {
          int t = m >> 5, b = m & 31;
          ((float*)Cout)[(size_t)b * (S_LEN * DIN) + t * DIN + n] = v;
        } else {
          int t = m >> 5, b = m & 31;
          ((ushort_t*)Cout)[(size_t)t * (N * 32) + n * 32 + b] = f2bf(v);
        }
      }
}

// ---------------------------------------------------------------------------
// Bidirectional LSTM recurrence — SINGLE-WG-PER-(dir,batch-half), zero
// cross-WG communication. Key insight: batches are independent in the
// recurrence (h_t[b] depends only on h_{t-1}[b]); only the H=256 column dim
// couples via h @ whh^T. So one 1024-thread WG (16 waves, one CU) owns a
// full direction for 16 batches: whh (4Hx256 bf16 = 512 KB) lives in
// registers (wave w holds the 4 gate-type B-frags for cols w*16..w*16+15:
// 4x8 short8 = 128 VGPRs), h_{t-1} in a double-buffered 17 KB LDS buffer,
// sync = ONE __syncthreads per step. No MALL, no polls, no tags.
// Grid = 4 WGs: dir = bx&1, bh = bx>>1 (batches bh*16..+15).
// Per step/wave: 8 ds_read_b128 (A-frags) + 32 MFMA + 4-element LSTM cell.
// ---------------------------------------------------------------------------
__global__ __launch_bounds__(1024) void lstm_layer(
    const ushort_t* __restrict__ xpf, const ushort_t* __restrict__ xpb,
    const ushort_t* __restrict__ whhf, const ushort_t* __restrict__ whhb,
    ushort_t* __restrict__ hout)
{
  const int dir = blockIdx.x & 1;
  const int bh  = blockIdx.x >> 1;      // batch half: batches bh*16..bh*16+15
  const int b0  = bh * 16;

  const ushort_t* xp  = dir ? xpb : xpf;
  const ushort_t* whh = dir ? whhb : whhf;
  const int hoff = dir * 256;

  __shared__ __align__(16) ushort_t hbuf[2][16 * 264];  // double-buffered h, stride 264

  const int tid = threadIdx.x, lane = tid & 63, w = tid >> 6;  // w = 0..15
  const int l15 = lane & 15, q4 = lane >> 4;
  const int col = w * 16 + l15;         // h column within this direction (0..255)

  // permanent B-fragments: wave w owns cols [w*16, w*16+16) of all 4 gate types
  short8 Bf[4][8];
#pragma unroll
  for (int gt = 0; gt < 4; ++gt)
#pragma unroll
    for (int ks = 0; ks < 8; ++ks)
      Bf[gt][ks] = *(const short8*)(whh + (size_t)(gt * 256 + col) * 256 + ks * 32 + q4 * 8);

  // zero hbuf[0] (h_{-1} = 0); step 0 reads buf[0]
  for (int i = tid; i < 16 * 132; i += 1024) ((uint_t*)&hbuf[0][0])[i] = 0u;

  float cst[4] = {0.f, 0.f, 0.f, 0.f};

  // xp prefetch: [t][g][b] layout; u64 = 4 consecutive batches at (g, b0+q4*4)
  u64 xr[4];
  auto ldxp = [&](int tt) {
#pragma unroll
    for (int gt = 0; gt < 4; ++gt)
      xr[gt] = *(const u64*)(xp + (size_t)tt * (GDIM * BATCH) + (size_t)(gt * 256 + col) * 32 + b0 + q4 * 4);
  };

  ldxp((dir == 0) ? 0 : 1023);
  __syncthreads();

  for (int sc = 0; sc < 1024; ++sc) {
    const int tcur  = (dir == 0) ? sc : 1023 - sc;
    const int tnext = (dir == 0) ? (sc < 1023 ? sc + 1 : 1023) : (sc < 1023 ? 1022 - sc : 0);

    floatx4 acc[4];
#pragma unroll
    for (int gt = 0; gt < 4; ++gt) {
      u64 v = xr[gt];
#pragma unroll
      for (int rr = 0; rr < 4; ++rr)
        acc[gt][rr] = bf2f((ushort_t)(v >> (16 * rr)));
    }

    ldxp(tnext);  // prefetch next step's xp (hidden under MFMA+cell)

    // ---- gates = xp + h_{t-1} @ whh^T : 32 MFMAs per wave ----
    const ushort_t* hb = &hbuf[sc & 1][0];
#pragma unroll
    for (int ks = 0; ks < 8; ++ks) {
      short8 a = *(const short8*)(hb + l15 * 264 + ks * 32 + q4 * 8);
      acc[0] = __builtin_amdgcn_mfma_f32_16x16x32_bf16(a, Bf[0][ks], acc[0], 0, 0, 0);
      acc[1] = __builtin_amdgcn_mfma_f32_16x16x32_bf16(a, Bf[1][ks], acc[1], 0, 0, 0);
      acc[2] = __builtin_amdgcn_mfma_f32_16x16x32_bf16(a, Bf[2][ks], acc[2], 0, 0, 0);
      acc[3] = __builtin_amdgcn_mfma_f32_16x16x32_bf16(a, Bf[3][ks], acc[3], 0, 0, 0);
    }

    // ---- LSTM cell in registers: lane owns (col, batches q4*4+rr) ----
    // C-layout: col = lane&15 (matches this lane's `col`), row = q4*4+rr.
    ushort_t* hw = &hbuf[(sc + 1) & 1][0];
#pragma unroll
    for (int rr = 0; rr < 4; ++rr) {
      float gi = acc[0][rr], gf = acc[1][rr], gg = acc[2][rr], go = acc[3][rr];
      float c = sigf(gf) * cst[rr] + sigf(gi) * tanh_f(gg);
      cst[rr] = c;
      float h = sigf(go) * tanh_f(c);
      ushort_t hb16 = f2bf(h);
      int row = q4 * 4 + rr;
      hw[row * 264 + col] = hb16;
      hout[(size_t)tcur * (BATCH * 512) + (size_t)(b0 + row) * 512 + hoff + col] = hb16;
    }
    __syncthreads();  // h_t complete in hbuf[(sc+1)&1] before next step reads it
  }
}

// ---------------------------------------------------------------------------
// Attention scores -> e = exp(s - max_t s), per batch b.
// ---------------------------------------------------------------------------
__global__ __launch_bounds__(256) void attn_scores(
    const ushort_t* __restrict__ h1, const float* __restrict__ attn_w,
    const float* __restrict__ attn_b, float* __restrict__ e_out)
{
  const int b = blockIdx.x;
  __shared__ float sbuf[1024];
  __shared__ float red[4];
  const int tid = threadIdx.x, lane = tid & 63, w = tid >> 6;

  float wreg[8];
#pragma unroll
  for (int i = 0; i < 8; ++i) wreg[i] = attn_w[lane * 8 + i];

  for (int t = w; t < 1024; t += 4) {
    short8 hv = *(const short8*)(h1 + (size_t)t * (BATCH * 512) + b * 512 + lane * 8);
    float dot = 0.f;
#pragma unroll
    for (int i = 0; i < 8; ++i) dot += bf2fs(hv[i]) * wreg[i];
#pragma unroll
    for (int off = 32; off; off >>= 1) dot += __shfl_xor(dot, off);
    if (lane == 0) sbuf[t] = dot + attn_b[0];
  }
  __syncthreads();
  float m = -1e30f;
  for (int t = tid; t < 1024; t += 256) m = fmaxf(m, sbuf[t]);
#pragma unroll
  for (int off = 32; off; off >>= 1) m = fmaxf(m, __shfl_xor(m, off));
  if (lane == 0) red[w] = m;
  __syncthreads();
  float mm = fmaxf(fmaxf(red[0], red[1]), fmaxf(red[2], red[3]));
  for (int t = tid; t < 1024; t += 256) e_out[b * 1024 + t] = __expf(sbuf[t] - mm);
}

// ---------------------------------------------------------------------------
// Cumulative context: ctx[t][b][c] = (sum_{u<=t} e_u h_u[c]) / (sum e_u), bf16.
// ---------------------------------------------------------------------------
__global__ __launch_bounds__(256) void attn_ctx(
    const ushort_t* __restrict__ h1, const float* __restrict__ e_in, ushort_t* __restrict__ ctx)
{
  const int b = blockIdx.x >> 1, half = blockIdx.x & 1;
  const int c = half * 256 + threadIdx.x;
  float num = 0.f, den = 0.f;
  const ushort_t* hp = h1 + b * 512 + c;
  ushort_t* cp = ctx + b * 512 + c;
  const float* ep = e_in + b * 1024;
#pragma unroll 4
  for (int t = 0; t < 1024; ++t) {
    float ev = ep[t];
    float hv = bf2f(hp[(size_t)t * (BATCH * 512)]);
    num += ev * hv;
    den += ev;
    cp[(size_t)t * (BATCH * 512)] = f2bf(num / den);
  }
}

// ---------------------------------------------------------------------------
// casts
// ---------------------------------------------------------------------------
__global__ void castw(const float* __restrict__ in, ushort_t* __restrict__ out, int n) {
  int i = blockIdx.x * 256 + threadIdx.x;
  if (i < n) out[i] = f2bf(in[i]);
}
__global__ void castx(const float* __restrict__ x, ushort_t* __restrict__ xt) {
  int i = blockIdx.x * 256 + threadIdx.x;  // over 32768*128
  int dcol = i & 127;
  int m = i >> 7;
  int b = m & 31, s = m >> 5;
  xt[i] = f2bf(x[(size_t)b * (S_LEN * DIN) + s * DIN + dcol]);
}

extern "C" void kernel_launch(void* const* d_in, const int* in_sizes, int n_in,
                              void* d_out, int out_size, void* d_ws, size_t ws_size,
                              hipStream_t stream)
{
  const float* x     = (const float*)d_in[0];
  const float* wih0f = (const float*)d_in[1];
  const float* whh0f = (const float*)d_in[2];
  const float* b0f   = (const float*)d_in[3];
  const float* wih0b = (const float*)d_in[4];
  const float* whh0b = (const float*)d_in[5];
  const float* b0b   = (const float*)d_in[6];
  const float* wih1f = (const float*)d_in[7];
  const float* whh1f = (const float*)d_in[8];
  const float* b1f   = (const float*)d_in[9];
  const float* wih1b = (const float*)d_in[10];
  const float* whh1b = (const float*)d_in[11];
  const float* b1b   = (const float*)d_in[12];
  const float* attw  = (const float*)d_in[13];
  const float* attb  = (const float*)d_in[14];
  const float* headw = (const float*)d_in[15];
  const float* headb = (const float*)d_in[16];
  float* out = (float*)d_out;

  char* p = (char*)d_ws;
  auto alloc = [&](size_t bytes) {
    char* r = p;
    p += (bytes + 511) & ~(size_t)511;
    return r;
  };
  ushort_t* xt    = (ushort_t*)alloc((size_t)32768 * 128 * 2);
  ushort_t* cwih0f = (ushort_t*)alloc(131072 * 2);
  ushort_t* cwih0b = (ushort_t*)alloc(131072 * 2);
  ushort_t* cwhh0f = (ushort_t*)alloc(262144 * 2);
  ushort_t* cwhh0b = (ushort_t*)alloc(262144 * 2);
  ushort_t* cwih1f = (ushort_t*)alloc(524288 * 2);
  ushort_t* cwih1b = (ushort_t*)alloc(524288 * 2);
  ushort_t* cwhh1f = (ushort_t*)alloc(262144 * 2);
  ushort_t* cwhh1b = (ushort_t*)alloc(262144 * 2);
  ushort_t* cwhead = (ushort_t*)alloc(65536 * 2);
  ushort_t* xpA = (ushort_t*)alloc((size_t)32768 * 1024 * 2);
  ushort_t* xpB = (ushort_t*)alloc((size_t)32768 * 1024 * 2);
  ushort_t* h0  = (ushort_t*)alloc((size_t)32768 * 512 * 2);
  ushort_t* h1  = (ushort_t*)alloc((size_t)32768 * 512 * 2);
  float* ebuf   = (float*)alloc(32 * 1024 * 4);
  ushort_t* ctx = xpA;  // reuse (xp dead by then)

  (void)in_sizes; (void)n_in; (void)out_size; (void)ws_size;

  castw<<<512, 256, 0, stream>>>(wih0f, cwih0f, 131072);
  castw<<<512, 256, 0, stream>>>(wih0b, cwih0b, 131072);
  castw<<<1024, 256, 0, stream>>>(whh0f, cwhh0f, 262144);
  castw<<<1024, 256, 0, stream>>>(whh0b, cwhh0b, 262144);
  castw<<<2048, 256, 0, stream>>>(wih1f, cwih1f, 524288);
  castw<<<2048, 256, 0, stream>>>(wih1b, cwih1b, 524288);
  castw<<<1024, 256, 0, stream>>>(whh1f, cwhh1f, 262144);
  castw<<<1024, 256, 0, stream>>>(whh1b, cwhh1b, 262144);
  castw<<<256, 256, 0, stream>>>(headw, cwhead, 65536);
  castx<<<16384, 256, 0, stream>>>(x, xt);

  // layer 0: xp in transposed [t][g][b] layout (mode 2)
  gemm_bf16<<<dim3(8, 256), 256, 0, stream>>>(xt, cwih0f, b0f, xpA, 32768, 1024, 128, 2);
  gemm_bf16<<<dim3(8, 256), 256, 0, stream>>>(xt, cwih0b, b0b, xpB, 32768, 1024, 128, 2);
  lstm_layer<<<4, 1024, 0, stream>>>(xpA, xpB, cwhh0f, cwhh0b, h0);

  // layer 1
  gemm_bf16<<<dim3(8, 256), 256, 0, stream>>>(h0, cwih1f, b1f, xpA, 32768, 1024, 512, 2);
  gemm_bf16<<<dim3(8, 256), 256, 0, stream>>>(h0, cwih1b, b1b, xpB, 32768, 1024, 512, 2);
  lstm_layer<<<4, 1024, 0, stream>>>(xpA, xpB, cwhh1f, cwhh1b, h1);

  // attention + head
  attn_scores<<<32, 256, 0, stream>>>(h1, attw, attb, ebuf);
  attn_ctx<<<64, 256, 0, stream>>>(h1, ebuf, ctx);
  gemm_bf16<<<dim3(1, 256), 256, 0, stream>>>(ctx, cwhead, headb, out, 32768, 128, 512, 1);
}